// Round 4
// baseline (17140.067 us; speedup 1.0000x reference)
//
#include <hip/hip_runtime.h>
#include <stdint.h>

#define SEQ   1000
#define BATCH 256
#define HID   256
#define NGATE 8
#define NTOT  (HID*NGATE)   /* 2048 */
#define KTOT  512           /* 256 (x) + 256 (m) */

typedef unsigned short u16;
typedef short  bf16x8 __attribute__((ext_vector_type(8)));
typedef short  bf16x4 __attribute__((ext_vector_type(4)));
typedef float  f32x4  __attribute__((ext_vector_type(4)));

static __device__ __forceinline__ u16 f2bf(float x){
  unsigned u = __float_as_uint(x);
  u += 0x7fffu + ((u >> 16) & 1u);
  return (u16)(u >> 16);
}
static __device__ __forceinline__ float bf2f(u16 h){
  return __uint_as_float(((unsigned)h) << 16);
}
static __device__ __forceinline__ float sigf(float x){
  return 1.0f / (1.0f + __expf(-x));
}
static __device__ __forceinline__ float tanh_fast(float x){
  float e = __expf(2.0f * x);
  return 1.0f - 2.0f / (e + 1.0f);
}

/* ---- one-time weight permute + hi/lo bf16 split ----
 * Wt[n][k], n = h*8 + g (gate-minor: one block owns all 8 gates of its h-slice)
 * k < 256 : W_ih[g][k][h]    (contracts with x_t)
 * k >= 256: W_hh[g][k-256][h] (contracts with m)
 */
__global__ __launch_bounds__(256) void prep_w(const float* __restrict__ wih,
                                              const float* __restrict__ whh,
                                              u16* __restrict__ Wthi,
                                              u16* __restrict__ Wtlo){
  int gid = blockIdx.x * 256 + threadIdx.x;      /* 0 .. 2048*512-1 */
  int n = gid >> 9, k = gid & 511;
  int h = n >> 3, g = n & 7;
  float v = (k < 256) ? wih[(g * 256 + k) * 256 + h]
                      : whh[(g * 256 + (k - 256)) * 256 + h];
  u16 hi = f2bf(v);
  Wthi[gid] = hi;
  Wtlo[gid] = f2bf(v - bf2f(hi));
}

__global__ __launch_bounds__(256) void init_state(float* __restrict__ c,
                                                  u16* __restrict__ mh,
                                                  u16* __restrict__ ml){
  int i = blockIdx.x * 256 + threadIdx.x;
  c[i]  = 1.0f;
  mh[i] = 0x3F80;  /* bf16(1.0) exactly */
  ml[i] = 0;
}

/* ---- one recurrence step ----
 * grid (64, 4): blockIdx.x -> n-tile (32 cols = 4 h x 8 g), blockIdx.y -> 64 batch rows
 * 256 threads = 4 waves; wave tile 32(M) x 16(N); K in 4 chunks of 128 via LDS.
 * 3-product split-bf16 MFMA (hi*hi + hi*lo + lo*hi).
 */
__global__ __launch_bounds__(256) void step_kernel(
    const float* __restrict__ xt,        /* [256][256] fp32, this timestep   */
    const u16*  __restrict__ mhi_in,     /* [256][256] bf16 hi of m          */
    const u16*  __restrict__ mlo_in,     /* [256][256] bf16 lo of m          */
    const u16*  __restrict__ Wthi,       /* [2048][512] */
    const u16*  __restrict__ Wtlo,
    float*      __restrict__ cbuf,       /* [256][256] fp32, in-place        */
    float*      __restrict__ mf_out,     /* [256][256] fp32 (= d_out)        */
    u16*        __restrict__ mhi_out,
    u16*        __restrict__ mlo_out){

  __shared__ __align__(16) u16  Ahi[64][128];
  __shared__ __align__(16) u16  Alo[64][128];
  __shared__ __align__(16) u16  Bhi[32][128];
  __shared__ __align__(16) u16  Blo[32][128];
  __shared__ float s_t[32][65];          /* s transposed: [n_local][b_local] */

  const int tid = threadIdx.x;
  const int n0 = blockIdx.x * 32;        /* N offset (h0*8) */
  const int h0 = blockIdx.x * 4;         /* hidden-col offset */
  const int b0 = blockIdx.y * 64;        /* batch-row offset */

  const int w    = tid >> 6;
  const int lane = tid & 63;
  const int wm = (w & 1) * 32;           /* wave M offset in tile */
  const int wn = (w >> 1) * 16;          /* wave N offset in tile */
  const int la = lane & 15;
  const int kg = (lane >> 4) * 8;        /* k sub-offset within 32 */
  const int ra0 = wm + la, ra1 = wm + 16 + la, rb = wn + la;

  f32x4 acc0 = {0.f, 0.f, 0.f, 0.f};
  f32x4 acc1 = {0.f, 0.f, 0.f, 0.f};

  for (int kc = 0; kc < 4; ++kc){
    const int ko = kc * 128;             /* global k offset of this chunk */
    if (kc) __syncthreads();

    /* ---- stage A chunk (64 rows x 128 k), XOR-swizzled in 16B units ----
       k<256 -> x_t (split hi/lo on the fly), k>=256 -> pre-split m        */
    if (ko < 256){
      const int xo = ko;
      for (int idx = tid; idx < 64 * 32; idx += 256){
        int r = idx >> 5, q = idx & 31;
        const float4 v = *(const float4*)(xt + (size_t)(b0 + r) * 256 + xo + q * 4);
        u16 h0_ = f2bf(v.x), h1_ = f2bf(v.y), h2_ = f2bf(v.z), h3_ = f2bf(v.w);
        bf16x4 vh = { (short)h0_, (short)h1_, (short)h2_, (short)h3_ };
        bf16x4 vl = { (short)f2bf(v.x - bf2f(h0_)), (short)f2bf(v.y - bf2f(h1_)),
                      (short)f2bf(v.z - bf2f(h2_)), (short)f2bf(v.w - bf2f(h3_)) };
        int su = ((q >> 1) ^ (r & 7));
        int ofs = (su << 3) + ((q & 1) << 2);
        *(bf16x4*)&Ahi[r][ofs] = vh;
        *(bf16x4*)&Alo[r][ofs] = vl;
      }
    } else {
      const int mo = ko - 256;
      for (int idx = tid; idx < 64 * 16; idx += 256){
        int r = idx >> 4, u = idx & 15;
        size_t go = (size_t)(b0 + r) * HID + mo + u * 8;
        bf16x8 vh = *(const bf16x8*)(mhi_in + go);
        bf16x8 vl = *(const bf16x8*)(mlo_in + go);
        int su = (u ^ (r & 7)) << 3;
        *(bf16x8*)&Ahi[r][su] = vh;
        *(bf16x8*)&Alo[r][su] = vl;
      }
    }
    /* ---- stage B chunk (32 n-rows x 128 k) from pre-split Wt ---- */
    for (int idx = tid; idx < 32 * 16; idx += 256){
      int r = idx >> 4, u = idx & 15;
      size_t go = (size_t)(n0 + r) * KTOT + ko + u * 8;
      bf16x8 vh = *(const bf16x8*)(Wthi + go);
      bf16x8 vl = *(const bf16x8*)(Wtlo + go);
      int su = (u ^ (r & 7)) << 3;
      *(bf16x8*)&Bhi[r][su] = vh;
      *(bf16x8*)&Blo[r][su] = vl;
    }
    __syncthreads();

    /* ---- MFMA over this chunk ---- */
    #pragma unroll
    for (int kk = 0; kk < 4; ++kk){
      const int k0 = kk * 32 + kg;       /* 0..127 within chunk */
      const int ua0 = ((k0 >> 3) ^ (ra0 & 7)) << 3;
      const int ua1 = ((k0 >> 3) ^ (ra1 & 7)) << 3;
      const int ub  = ((k0 >> 3) ^ (rb  & 7)) << 3;
      bf16x8 a0h = *(const bf16x8*)&Ahi[ra0][ua0];
      bf16x8 a0l = *(const bf16x8*)&Alo[ra0][ua0];
      bf16x8 a1h = *(const bf16x8*)&Ahi[ra1][ua1];
      bf16x8 a1l = *(const bf16x8*)&Alo[ra1][ua1];
      bf16x8 bh  = *(const bf16x8*)&Bhi[rb][ub];
      bf16x8 bl  = *(const bf16x8*)&Blo[rb][ub];
      acc0 = __builtin_amdgcn_mfma_f32_16x16x32_bf16(a0h, bh, acc0, 0, 0, 0);
      acc0 = __builtin_amdgcn_mfma_f32_16x16x32_bf16(a0h, bl, acc0, 0, 0, 0);
      acc0 = __builtin_amdgcn_mfma_f32_16x16x32_bf16(a0l, bh, acc0, 0, 0, 0);
      acc1 = __builtin_amdgcn_mfma_f32_16x16x32_bf16(a1h, bh, acc1, 0, 0, 0);
      acc1 = __builtin_amdgcn_mfma_f32_16x16x32_bf16(a1h, bl, acc1, 0, 0, 0);
      acc1 = __builtin_amdgcn_mfma_f32_16x16x32_bf16(a1l, bh, acc1, 0, 0, 0);
    }
  }

  /* ---- write s (transposed) to LDS: C layout col=lane&15, row=(lane>>4)*4+r ---- */
  {
    const int fq = (lane >> 4) * 4;
    #pragma unroll
    for (int r = 0; r < 4; ++r){
      s_t[wn + la][wm + fq + r]      = acc0[r];
      s_t[wn + la][wm + 16 + fq + r] = acc1[r];
    }
  }
  __syncthreads();

  /* ---- pointwise NAS cell: one thread per (b_local, h_local) ---- */
  {
    const int bl = tid >> 2, hl = tid & 3;
    float s0 = s_t[hl * 8 + 0][bl];
    float s1 = s_t[hl * 8 + 1][bl];
    float s2 = s_t[hl * 8 + 2][bl];
    float s3 = s_t[hl * 8 + 3][bl];
    float s4 = s_t[hl * 8 + 4][bl];
    float s5 = s_t[hl * 8 + 5][bl];
    float s6 = s_t[hl * 8 + 6][bl];
    float s7 = s_t[hl * 8 + 7][bl];

    size_t off = (size_t)(b0 + bl) * HID + (h0 + hl);
    float c_old = cbuf[off];

    float l10 = sigf(s0);
    float l11 = fmaxf(s1, 0.0f);
    float l12 = sigf(s2);
    float l13 = fmaxf(s3, 0.0f);
    float l14 = tanh_fast(s4);
    float l15 = sigf(s5);
    float l16 = tanh_fast(s6);
    float l17 = sigf(s7);

    float l20 = tanh_fast(l10 * l11);
    float l21 = tanh_fast(l12 + l13);
    float l22 = tanh_fast(l14 * l15);
    float l23 = sigf(l16 + l17);

    float l20v2 = tanh_fast(l20 + c_old);
    float new_c = l20v2 * l21;
    float l31   = tanh_fast(l22 + l23);
    float new_m = tanh_fast(new_c * l31);

    cbuf[off]   = new_c;
    mf_out[off] = new_m;
    u16 mh = f2bf(new_m);
    mhi_out[off] = mh;
    mlo_out[off] = f2bf(new_m - bf2f(mh));
  }
}

extern "C" void kernel_launch(void* const* d_in, const int* in_sizes, int n_in,
                              void* d_out, int out_size, void* d_ws, size_t ws_size,
                              hipStream_t stream){
  const float* x   = (const float*)d_in[0];  /* [1000][256][256] */
  const float* wih = (const float*)d_in[1];  /* [8][256][256]    */
  const float* whh = (const float*)d_in[2];  /* [8][256][256]    */
  float* out = (float*)d_out;                /* [256][256] fp32  */

  /* workspace layout */
  u16* ws16 = (u16*)d_ws;
  u16* Wthi = ws16;                        /* 2048*512 u16                 */
  u16* Wtlo = Wthi + (size_t)NTOT * KTOT;  /* 2048*512 u16                 */
  u16* mhi  = Wtlo + (size_t)NTOT * KTOT;  /* 2 * 65536 u16 (ping-pong)    */
  u16* mlo  = mhi + 2 * 65536;             /* 2 * 65536 u16 (ping-pong)    */
  float* cbuf = (float*)(mlo + 2 * 65536); /* 65536 fp32                   */
  size_t need = (size_t)(2 * NTOT * KTOT + 4 * 65536) * sizeof(u16)
              + (size_t)65536 * sizeof(float);   /* ~4.98 MB */
  if (ws_size < need) return;

  hipLaunchKernelGGL(prep_w, dim3((NTOT * KTOT) / 256), dim3(256), 0, stream,
                     wih, whh, Wthi, Wtlo);
  hipLaunchKernelGGL(init_state, dim3(65536 / 256), dim3(256), 0, stream,
                     cbuf, mhi, mlo);

  for (int t = 0; t < SEQ; ++t){
    int rb = t & 1, wb = rb ^ 1;
    hipLaunchKernelGGL(step_kernel, dim3(64, 4), dim3(256), 0, stream,
                       x + (size_t)t * BATCH * 256,
                       mhi + (size_t)rb * 65536, mlo + (size_t)rb * 65536,
                       Wthi, Wtlo, cbuf,
                       out,                               /* m as fp32 -> d_out */
                       mhi + (size_t)wb * 65536, mlo + (size_t)wb * 65536);
  }
}